// Round 1
// baseline (386.418 us; speedup 1.0000x reference)
//
#include <hip/hip_runtime.h>

#define NM 4096
#define NK 16
#define NC 64

typedef __attribute__((ext_vector_type(8))) short s8v;
typedef __attribute__((ext_vector_type(4))) float f4v;
typedef __attribute__((ext_vector_type(2))) unsigned int u2v;

__device__ __forceinline__ short f2bf(float f) {
  unsigned u = __builtin_bit_cast(unsigned, f);
  u += 0x7fffu + ((u >> 16) & 1u);          // round-to-nearest-even
  return (short)(u >> 16);
}
__device__ __forceinline__ float bf2f(unsigned short s) {
  return __builtin_bit_cast(float, ((unsigned)s) << 16);
}
__device__ __forceinline__ unsigned pk2(float a, float b) {
  return (unsigned)(unsigned short)f2bf(a) | ((unsigned)(unsigned short)f2bf(b) << 16);
}
__device__ __forceinline__ s8v pack8(f4v a, f4v b) {
  s8v r;
  r[0]=f2bf(a[0]); r[1]=f2bf(a[1]); r[2]=f2bf(a[2]); r[3]=f2bf(a[3]);
  r[4]=f2bf(b[0]); r[5]=f2bf(b[1]); r[6]=f2bf(b[2]); r[7]=f2bf(b[3]);
  return r;
}

#define MFMA(a,b,c) __builtin_amdgcn_mfma_f32_16x16x32_bf16((a),(b),(c),0,0,0)

#define HSTRIDE 72                 // shorts per row: 64 + pad, multiple of 8 (16B align), 72->even bank spread
#define TBUF_SHORTS (16*HSTRIDE)   // 1152 shorts = 2304 B per wave

__global__ __launch_bounds__(256, 2)
void lattn_kernel(const float* __restrict__ x,  const float* __restrict__ xyz,
                  const float* __restrict__ Wq, const float* __restrict__ bq,
                  const float* __restrict__ Wk, const float* __restrict__ bk,
                  const float* __restrict__ Wv, const float* __restrict__ bv,
                  const float* __restrict__ Wp1,const float* __restrict__ bp1,
                  const float* __restrict__ Wp2,const float* __restrict__ bp2,
                  const float* __restrict__ Wa1,const float* __restrict__ ba1,
                  const float* __restrict__ Wa2,const float* __restrict__ ba2,
                  const float* __restrict__ W2, const float* __restrict__ b2,
                  float* __restrict__ out) {
  // LDS: weights (frag-linear bf16) + per-wave q/res buffer + per-wave RT buffer
  __shared__ __align__(16) short wlds[5*8*64*8];      // 40960 B
  __shared__ __align__(16) short qres[4*TBUF_SHORTS]; // 9216 B
  __shared__ __align__(16) short hbuf[4*TBUF_SHORTS]; // 9216 B

  const int tid = threadIdx.x;

  // ---- stage 5 weight matrices into LDS, bf16, frag-linear ----
  // slot idx = mat*512 + (t*2+h)*64 + lane ; element j -> k' = h*32 + q*8 + j
  // Wp2/Wa1/Wa2 consume round-tripped activations whose features are written
  // permuted sigma(16t+c)=4c+t, so their k index is gathered: k = ((k'&3)<<4)|(k'>>2)
  for (int idx = tid; idx < 5*8*64; idx += 256) {
    const int mat = idx >> 9;
    const int rem = idx & 511;
    const int f   = rem >> 6;
    const int ln  = rem & 63;
    const int t = f >> 1, h = f & 1;
    const int cc = ln & 15, qq = ln >> 4;
    const int n = 16*t + cc;
    const float* W = (mat==0) ? Wk : (mat==1) ? Wv : (mat==2) ? Wp2 : (mat==3) ? Wa1 : Wa2;
    const bool prm = (mat >= 2);
    s8v v;
    #pragma unroll
    for (int j = 0; j < 8; ++j) {
      int kp = h*32 + qq*8 + j;
      int k = prm ? (((kp & 3) << 4) | (kp >> 2)) : kp;
      v[j] = f2bf(W[n*64 + k]);
    }
    *(s8v*)&wlds[(size_t)idx * 8] = v;
  }
  __syncthreads();

  const int w    = tid >> 6;
  const int lane = tid & 63;
  const int c    = lane & 15;   // A-row (neighbor) / C-col (feature offset)
  const int lq   = lane >> 4;   // lane quad

  const int gw  = blockIdx.x * 4 + w;   // 0..2047 waves
  const int gp0 = gw << 4;              // 16 points per wave
  const int b   = gp0 >> 12;
  const int m0  = gp0 & (NM - 1);

  short* qbuf = qres + w * TBUF_SHORTS;
  short* hb   = hbuf + w * TBUF_SHORTS;

  // ---- per-wave constants: Wp1 frags (K=3 padded to 32) and biases ----
  s8v wp1f[4];
  float bp1f[4], bkf[4], bvf[4], bp2f[4], ba1f[4], ba2f[4], bqf[4], b2f[4];
  #pragma unroll
  for (int t = 0; t < 4; ++t) {
    const int n = 16*t + c;
    s8v v = {0,0,0,0,0,0,0,0};
    if (lq == 0) { v[0] = f2bf(Wp1[n*3+0]); v[1] = f2bf(Wp1[n*3+1]); v[2] = f2bf(Wp1[n*3+2]); }
    wp1f[t] = v;
    bp1f[t] = bp1[n]; bkf[t] = bk[n]; bvf[t] = bv[n];
    bp2f[t] = bp2[n]; ba1f[t] = ba1[n]; ba2f[t] = ba2[n];
    bqf[t] = bq[n];   b2f[t] = b2[n];
  }

  const long ptbase = (long)(b * NM + m0);

  // ---- group q phase: q = raw_feature @ Wq^T + bq for the 16 points ----
  {
    const float* xr = x + (ptbase + c) * (long)(NK*NC) + 8*lq;  // neighbor-0 row of point c
    s8v rA0 = pack8(*(const f4v*)xr,        *(const f4v*)(xr+4));
    s8v rA1 = pack8(*(const f4v*)(xr+32),   *(const f4v*)(xr+36));
    #pragma unroll
    for (int t = 0; t < 4; ++t) {
      const float* wr = Wq + (16*t + c)*64 + 8*lq;
      s8v w0 = pack8(*(const f4v*)wr,       *(const f4v*)(wr+4));
      s8v w1 = pack8(*(const f4v*)(wr+32),  *(const f4v*)(wr+36));
      f4v acc = {bqf[t], bqf[t], bqf[t], bqf[t]};
      acc = MFMA(rA0, w0, acc);
      acc = MFMA(rA1, w1, acc);
      #pragma unroll
      for (int r = 0; r < 4; ++r)
        qbuf[(4*lq + r)*HSTRIDE + 16*t + c] = f2bf(acc[r]);   // q[point 4lq+r][16t+c]
    }
  }

  // ---- per-point pipeline ----
  for (int p = 0; p < 16; ++p) {
    const long prow = ptbase + p;
    const float* xr = x + prow * (long)(NK*NC) + c*NC + 8*lq;   // neighbor c, cols 8lq..
    s8v xA0 = pack8(*(const f4v*)xr,      *(const f4v*)(xr+4));
    s8v xA1 = pack8(*(const f4v*)(xr+32), *(const f4v*)(xr+36));

    const float* zp = xyz + prow * (long)(NK*3);
    const float rx = zp[c*3+0] - zp[0];
    const float ry = zp[c*3+1] - zp[1];
    const float rz = zp[c*3+2] - zp[2];
    s8v relf = {0,0,0,0,0,0,0,0};
    if (lq == 0) { relf[0] = f2bf(rx); relf[1] = f2bf(ry); relf[2] = f2bf(rz); }

    // pos1 = relu(rel @ Wp1^T + bp1)   (K padded with zeros)
    f4v p1[4];
    #pragma unroll
    for (int t = 0; t < 4; ++t) {
      f4v acc = {bp1f[t], bp1f[t], bp1f[t], bp1f[t]};
      acc = MFMA(relf, wp1f[t], acc);
      #pragma unroll
      for (int r = 0; r < 4; ++r) acc[r] = fmaxf(acc[r], 0.0f);
      p1[t] = acc;
    }
    // C->A round trip (permuted cols: feature 16t+c -> col 4c+t)
    #pragma unroll
    for (int r = 0; r < 4; ++r) {
      u2v pv = { pk2(p1[0][r], p1[1][r]), pk2(p1[2][r], p1[3][r]) };
      *(u2v*)&hb[(4*lq + r)*HSTRIDE + 4*c] = pv;
    }
    s8v pA0 = *(const s8v*)&hb[c*HSTRIDE + 8*lq];
    s8v pA1 = *(const s8v*)&hb[c*HSTRIDE + 32 + 8*lq];

    // pos_enc = pos1 @ Wp2^T + bp2   (Wp2 k-permuted in LDS)
    f4v pe[4];
    #pragma unroll
    for (int t = 0; t < 4; ++t) {
      const short* wb = &wlds[(2*512 + 2*t*64 + lane) * 8];
      s8v w0 = *(const s8v*)wb;
      s8v w1 = *(const s8v*)(wb + 512);
      f4v acc = {bp2f[t], bp2f[t], bp2f[t], bp2f[t]};
      acc = MFMA(pA0, w0, acc);
      acc = MFMA(pA1, w1, acc);
      pe[t] = acc;
    }

    // k = x @ Wk^T + bk ;  h = q - k + pos_enc
    f4v hC[4];
    #pragma unroll
    for (int t = 0; t < 4; ++t) {
      const short* wb = &wlds[(0*512 + 2*t*64 + lane) * 8];
      s8v w0 = *(const s8v*)wb;
      s8v w1 = *(const s8v*)(wb + 512);
      f4v acc = {bkf[t], bkf[t], bkf[t], bkf[t]};
      acc = MFMA(xA0, w0, acc);
      acc = MFMA(xA1, w1, acc);
      const float qv = bf2f((unsigned short)qbuf[p*HSTRIDE + 16*t + c]);
      #pragma unroll
      for (int r = 0; r < 4; ++r) hC[t][r] = qv - acc[r] + pe[t][r];
    }
    #pragma unroll
    for (int r = 0; r < 4; ++r) {
      u2v pv = { pk2(hC[0][r], hC[1][r]), pk2(hC[2][r], hC[3][r]) };
      *(u2v*)&hb[(4*lq + r)*HSTRIDE + 4*c] = pv;
    }
    s8v hA0 = *(const s8v*)&hb[c*HSTRIDE + 8*lq];
    s8v hA1 = *(const s8v*)&hb[c*HSTRIDE + 32 + 8*lq];

    // a1 = relu(h @ Wa1^T + ba1)   (Wa1 k-permuted)
    f4v a1[4];
    #pragma unroll
    for (int t = 0; t < 4; ++t) {
      const short* wb = &wlds[(3*512 + 2*t*64 + lane) * 8];
      s8v w0 = *(const s8v*)wb;
      s8v w1 = *(const s8v*)(wb + 512);
      f4v acc = {ba1f[t], ba1f[t], ba1f[t], ba1f[t]};
      acc = MFMA(hA0, w0, acc);
      acc = MFMA(hA1, w1, acc);
      #pragma unroll
      for (int r = 0; r < 4; ++r) acc[r] = fmaxf(acc[r], 0.0f);
      a1[t] = acc;
    }
    #pragma unroll
    for (int r = 0; r < 4; ++r) {
      u2v pv = { pk2(a1[0][r], a1[1][r]), pk2(a1[2][r], a1[3][r]) };
      *(u2v*)&hb[(4*lq + r)*HSTRIDE + 4*c] = pv;
    }
    s8v aA0 = *(const s8v*)&hb[c*HSTRIDE + 8*lq];
    s8v aA1 = *(const s8v*)&hb[c*HSTRIDE + 32 + 8*lq];

    // logits = a1 @ Wa2^T + ba2   (Wa2 k-permuted)
    f4v lg[4];
    #pragma unroll
    for (int t = 0; t < 4; ++t) {
      const short* wb = &wlds[(4*512 + 2*t*64 + lane) * 8];
      s8v w0 = *(const s8v*)wb;
      s8v w1 = *(const s8v*)(wb + 512);
      f4v acc = {ba2f[t], ba2f[t], ba2f[t], ba2f[t]};
      acc = MFMA(aA0, w0, acc);
      acc = MFMA(aA1, w1, acc);
      lg[t] = acc;
    }

    // softmax over the 16 neighbors (C-layout rows), per feature column
    // softmax(l/8): exp2((l-max)*log2(e)/8)
    f4v at[4];
    #pragma unroll
    for (int t = 0; t < 4; ++t) {
      f4v l = lg[t];
      float mx = fmaxf(fmaxf(l[0], l[1]), fmaxf(l[2], l[3]));
      mx = fmaxf(mx, __shfl_xor(mx, 16));
      mx = fmaxf(mx, __shfl_xor(mx, 32));
      f4v e;
      #pragma unroll
      for (int r = 0; r < 4; ++r) e[r] = exp2f((l[r] - mx) * 0.18033688011112043f);
      float s = e[0] + e[1] + e[2] + e[3];
      s += __shfl_xor(s, 16);
      s += __shfl_xor(s, 32);
      const float ri = 1.0f / s;
      #pragma unroll
      for (int r = 0; r < 4; ++r) at[t][r] = e[r] * ri;
    }

    // v = x @ Wv^T + bv ; res[f] = sum_m attn[m][f]*(v+pos_enc)[m][f]
    float res[4];
    #pragma unroll
    for (int t = 0; t < 4; ++t) {
      const short* wb = &wlds[(1*512 + 2*t*64 + lane) * 8];
      s8v w0 = *(const s8v*)wb;
      s8v w1 = *(const s8v*)(wb + 512);
      f4v acc = {bvf[t], bvf[t], bvf[t], bvf[t]};
      acc = MFMA(xA0, w0, acc);
      acc = MFMA(xA1, w1, acc);
      float pr = 0.0f;
      #pragma unroll
      for (int r = 0; r < 4; ++r) pr += at[t][r] * (acc[r] + pe[t][r]);
      pr += __shfl_xor(pr, 16);
      pr += __shfl_xor(pr, 32);
      res[t] = pr;
    }
    if (lq == 0) {
      #pragma unroll
      for (int t = 0; t < 4; ++t)
        qbuf[p*HSTRIDE + 16*t + c] = f2bf(res[t]);   // row p reused: q[p] is dead
    }
  }

  // ---- group final: out = res @ W2^T + b2 + raw_feature ----
  {
    s8v resA0 = *(const s8v*)&qbuf[c*HSTRIDE + 8*lq];
    s8v resA1 = *(const s8v*)&qbuf[c*HSTRIDE + 32 + 8*lq];
    #pragma unroll
    for (int t = 0; t < 4; ++t) {
      const float* wr = W2 + (16*t + c)*64 + 8*lq;
      s8v w0 = pack8(*(const f4v*)wr,      *(const f4v*)(wr+4));
      s8v w1 = pack8(*(const f4v*)(wr+32), *(const f4v*)(wr+36));
      f4v acc = {b2f[t], b2f[t], b2f[t], b2f[t]};
      acc = MFMA(resA0, w0, acc);
      acc = MFMA(resA1, w1, acc);
      #pragma unroll
      for (int r = 0; r < 4; ++r) {
        const long pr2 = ptbase + 4*lq + r;
        out[pr2*NC + 16*t + c] = acc[r] + x[pr2*(long)(NK*NC) + 16*t + c];
      }
    }
  }
}

extern "C" void kernel_launch(void* const* d_in, const int* in_sizes, int n_in,
                              void* d_out, int out_size, void* d_ws, size_t ws_size,
                              hipStream_t stream) {
  (void)in_sizes; (void)n_in; (void)out_size; (void)d_ws; (void)ws_size;
  const float* x   = (const float*)d_in[0];
  const float* xyz = (const float*)d_in[1];
  const float* Wq  = (const float*)d_in[2];
  const float* bq  = (const float*)d_in[3];
  const float* Wk  = (const float*)d_in[4];
  const float* bk  = (const float*)d_in[5];
  const float* Wv  = (const float*)d_in[6];
  const float* bv  = (const float*)d_in[7];
  const float* Wp1 = (const float*)d_in[8];
  const float* bp1 = (const float*)d_in[9];
  const float* Wp2 = (const float*)d_in[10];
  const float* bp2 = (const float*)d_in[11];
  const float* Wa1 = (const float*)d_in[12];
  const float* ba1 = (const float*)d_in[13];
  const float* Wa2 = (const float*)d_in[14];
  const float* ba2 = (const float*)d_in[15];
  const float* W2  = (const float*)d_in[16];
  const float* b2  = (const float*)d_in[17];
  float* out = (float*)d_out;

  // 8*4096 points / 16 per wave / 4 waves per block = 512 blocks
  lattn_kernel<<<dim3(512), dim3(256), 0, stream>>>(
      x, xyz, Wq, bq, Wk, bk, Wv, bv, Wp1, bp1, Wp2, bp2,
      Wa1, ba1, Wa2, ba2, W2, b2, out);
}

// Round 2
// 384.823 us; speedup vs baseline: 1.0041x; 1.0041x over previous
//
#include <hip/hip_runtime.h>

#define NM 4096
#define NK 16
#define NC 64

typedef __attribute__((ext_vector_type(8))) short s8v;
typedef __attribute__((ext_vector_type(4))) float f4v;
typedef __attribute__((ext_vector_type(2))) unsigned int u2v;

__device__ __forceinline__ short f2bf(float f) {
  unsigned u = __builtin_bit_cast(unsigned, f);
  u += 0x7fffu + ((u >> 16) & 1u);          // round-to-nearest-even
  return (short)(u >> 16);
}
__device__ __forceinline__ float bf2f(unsigned short s) {
  return __builtin_bit_cast(float, ((unsigned)s) << 16);
}
__device__ __forceinline__ unsigned pk2(float a, float b) {
  return (unsigned)(unsigned short)f2bf(a) | ((unsigned)(unsigned short)f2bf(b) << 16);
}
__device__ __forceinline__ s8v pack8(f4v a, f4v b) {
  s8v r;
  r[0]=f2bf(a[0]); r[1]=f2bf(a[1]); r[2]=f2bf(a[2]); r[3]=f2bf(a[3]);
  r[4]=f2bf(b[0]); r[5]=f2bf(b[1]); r[6]=f2bf(b[2]); r[7]=f2bf(b[3]);
  return r;
}

#define MFMA(a,b,c) __builtin_amdgcn_mfma_f32_16x16x32_bf16((a),(b),(c),0,0,0)

#define HSTRIDE 72                 // shorts per row: 64 + pad, 16B-aligned rows, 2-way-max banks
#define TBUF_SHORTS (16*HSTRIDE)   // 1152 shorts = 2304 B

__global__ __launch_bounds__(256, 2)
void lattn_kernel(const float* __restrict__ x,  const float* __restrict__ xyz,
                  const float* __restrict__ Wq, const float* __restrict__ bq,
                  const float* __restrict__ Wk, const float* __restrict__ bk,
                  const float* __restrict__ Wv, const float* __restrict__ bv,
                  const float* __restrict__ Wp1,const float* __restrict__ bp1,
                  const float* __restrict__ Wp2,const float* __restrict__ bp2,
                  const float* __restrict__ Wa1,const float* __restrict__ ba1,
                  const float* __restrict__ Wa2,const float* __restrict__ ba2,
                  const float* __restrict__ W2, const float* __restrict__ b2,
                  float* __restrict__ out) {
  // LDS: 4 weight mats (Wk,Wp2,Wa1,Wa2) frag-linear bf16 + q/res buf + 2 RT bufs/wave
  __shared__ __align__(16) short wlds[4*8*64*8];      // 32768 B
  __shared__ __align__(16) short qres[4*TBUF_SHORTS]; // 9216 B
  __shared__ __align__(16) short hbuf[8*TBUF_SHORTS]; // 18432 B  (2 per wave)

  const int tid = threadIdx.x;

  // ---- stage 4 weight matrices into LDS, bf16, frag-linear ----
  // slot idx = mat*512 + (t*2+h)*64 + lane ; element j -> k' = h*32 + q*8 + j
  // Wp2/Wa1/Wa2 consume sigma-permuted activations: k = ((k'&3)<<4)|(k'>>2)
  for (int idx = tid; idx < 4*8*64; idx += 256) {
    const int mat = idx >> 9;
    const int rem = idx & 511;
    const int f   = rem >> 6;
    const int ln  = rem & 63;
    const int t = f >> 1, h = f & 1;
    const int cc = ln & 15, qq = ln >> 4;
    const int n = 16*t + cc;
    const float* W = (mat==0) ? Wk : (mat==1) ? Wp2 : (mat==2) ? Wa1 : Wa2;
    const bool prm = (mat >= 1);
    s8v v;
    #pragma unroll
    for (int j = 0; j < 8; ++j) {
      int kp = h*32 + qq*8 + j;
      int k = prm ? (((kp & 3) << 4) | (kp >> 2)) : kp;
      v[j] = f2bf(W[n*64 + k]);
    }
    *(s8v*)&wlds[(size_t)idx * 8] = v;
  }
  __syncthreads();

  const int w    = tid >> 6;
  const int lane = tid & 63;
  const int c    = lane & 15;
  const int lq   = lane >> 4;

  const int gw  = blockIdx.x * 4 + w;
  const int gp0 = gw << 4;
  const int b   = gp0 >> 12;
  const int m0  = gp0 & (NM - 1);

  short* qbuf = qres + w * TBUF_SHORTS;
  short* hb0  = hbuf + (2*w) * TBUF_SHORTS;
  short* hb1  = hb0 + TBUF_SHORTS;

  // ---- loop-invariant registers: Wv frags, Wp1 frags, biases ----
  s8v wvf[8];
  #pragma unroll
  for (int t = 0; t < 4; ++t) {
    const float* wr = Wv + (16*t + c)*64 + 8*lq;
    wvf[2*t+0] = pack8(*(const f4v*)wr,      *(const f4v*)(wr+4));
    wvf[2*t+1] = pack8(*(const f4v*)(wr+32), *(const f4v*)(wr+36));
  }
  s8v wp1f[4];
  float bp1f[4], bkf[4], bvf[4], bp2f[4], ba1f[4], ba2f[4], bqf[4], b2f[4];
  #pragma unroll
  for (int t = 0; t < 4; ++t) {
    const int n = 16*t + c;
    s8v v = {0,0,0,0,0,0,0,0};
    if (lq == 0) { v[0] = f2bf(Wp1[n*3+0]); v[1] = f2bf(Wp1[n*3+1]); v[2] = f2bf(Wp1[n*3+2]); }
    wp1f[t] = v;
    bp1f[t] = bp1[n]; bkf[t] = bk[n]; bvf[t] = bv[n];
    bp2f[t] = bp2[n]; ba1f[t] = ba1[n]; ba2f[t] = ba2[n];
    bqf[t] = bq[n];   b2f[t] = b2[n];
  }

  const long ptbase = (long)(b * NM + m0);

  // ---- group q phase ----
  {
    const float* xr = x + (ptbase + c) * (long)(NK*NC) + 8*lq;
    s8v rA0 = pack8(*(const f4v*)xr,        *(const f4v*)(xr+4));
    s8v rA1 = pack8(*(const f4v*)(xr+32),   *(const f4v*)(xr+36));
    #pragma unroll
    for (int t = 0; t < 4; ++t) {
      const float* wr = Wq + (16*t + c)*64 + 8*lq;
      s8v w0 = pack8(*(const f4v*)wr,       *(const f4v*)(wr+4));
      s8v w1 = pack8(*(const f4v*)(wr+32),  *(const f4v*)(wr+36));
      f4v acc = {bqf[t], bqf[t], bqf[t], bqf[t]};
      acc = MFMA(rA0, w0, acc);
      acc = MFMA(rA1, w1, acc);
      #pragma unroll
      for (int r = 0; r < 4; ++r)
        qbuf[(4*lq + r)*HSTRIDE + 16*t + c] = f2bf(acc[r]);
    }
  }

  // ---- prefetch state for pair of points ----
  s8v  nx[2][2];
  float nza[2][3], nzb[2][3];
  {
    #pragma unroll
    for (int u = 0; u < 2; ++u) {
      const long prow = ptbase + u;
      const float* xr = x + prow * (long)(NK*NC) + c*NC + 8*lq;
      nx[u][0] = pack8(*(const f4v*)xr,      *(const f4v*)(xr+4));
      nx[u][1] = pack8(*(const f4v*)(xr+32), *(const f4v*)(xr+36));
      const float* zp = xyz + prow * (long)(NK*3);
      nza[u][0] = zp[c*3+0]; nza[u][1] = zp[c*3+1]; nza[u][2] = zp[c*3+2];
      nzb[u][0] = zp[0];     nzb[u][1] = zp[1];     nzb[u][2] = zp[2];
    }
  }

  // ---- main loop: 2 points per iteration, interleaved chains ----
  #pragma unroll 1
  for (int pp = 0; pp < 16; pp += 2) {
    s8v  xA[2][2];
    float rl[2][3];
    #pragma unroll
    for (int u = 0; u < 2; ++u) {
      xA[u][0] = nx[u][0]; xA[u][1] = nx[u][1];
      rl[u][0] = nza[u][0] - nzb[u][0];
      rl[u][1] = nza[u][1] - nzb[u][1];
      rl[u][2] = nza[u][2] - nzb[u][2];
    }
    if (pp < 14) {
      #pragma unroll
      for (int u = 0; u < 2; ++u) {
        const long prow = ptbase + pp + 2 + u;
        const float* xr = x + prow * (long)(NK*NC) + c*NC + 8*lq;
        nx[u][0] = pack8(*(const f4v*)xr,      *(const f4v*)(xr+4));
        nx[u][1] = pack8(*(const f4v*)(xr+32), *(const f4v*)(xr+36));
        const float* zp = xyz + prow * (long)(NK*3);
        nza[u][0] = zp[c*3+0]; nza[u][1] = zp[c*3+1]; nza[u][2] = zp[c*3+2];
        nzb[u][0] = zp[0];     nzb[u][1] = zp[1];     nzb[u][2] = zp[2];
      }
    }

    short* const HB[2] = { hb0, hb1 };

    // pos1 = relu(rel @ Wp1^T + bp1) for both points, then RT write+read
    s8v pA[2][2];
    {
      f4v p1[2][4];
      #pragma unroll
      for (int u = 0; u < 2; ++u) {
        s8v relf = {0,0,0,0,0,0,0,0};
        if (lq == 0) { relf[0] = f2bf(rl[u][0]); relf[1] = f2bf(rl[u][1]); relf[2] = f2bf(rl[u][2]); }
        #pragma unroll
        for (int t = 0; t < 4; ++t) {
          f4v acc = {bp1f[t], bp1f[t], bp1f[t], bp1f[t]};
          acc = MFMA(relf, wp1f[t], acc);
          #pragma unroll
          for (int r = 0; r < 4; ++r) acc[r] = fmaxf(acc[r], 0.0f);
          p1[u][t] = acc;
        }
      }
      #pragma unroll
      for (int u = 0; u < 2; ++u)
        #pragma unroll
        for (int r = 0; r < 4; ++r) {
          u2v pv = { pk2(p1[u][0][r], p1[u][1][r]), pk2(p1[u][2][r], p1[u][3][r]) };
          *(u2v*)&HB[u][(4*lq + r)*HSTRIDE + 4*c] = pv;
        }
      #pragma unroll
      for (int u = 0; u < 2; ++u) {
        pA[u][0] = *(const s8v*)&HB[u][c*HSTRIDE + 8*lq];
        pA[u][1] = *(const s8v*)&HB[u][c*HSTRIDE + 32 + 8*lq];
      }
    }

    // pos_enc = pos1 @ Wp2^T + bp2  (shared frag reads, mat1)
    f4v pe[2][4];
    #pragma unroll
    for (int t = 0; t < 4; ++t) {
      const short* wb = &wlds[(1*512 + 2*t*64 + lane) * 8];
      s8v w0 = *(const s8v*)wb;
      s8v w1 = *(const s8v*)(wb + 512);
      #pragma unroll
      for (int u = 0; u < 2; ++u) {
        f4v acc = {bp2f[t], bp2f[t], bp2f[t], bp2f[t]};
        acc = MFMA(pA[u][0], w0, acc);
        acc = MFMA(pA[u][1], w1, acc);
        pe[u][t] = acc;
      }
    }

    // k matmul (mat0) ; h = q - k + pos_enc ; RT
    s8v hA[2][2];
    {
      f4v hC[2][4];
      #pragma unroll
      for (int t = 0; t < 4; ++t) {
        const short* wb = &wlds[(0*512 + 2*t*64 + lane) * 8];
        s8v w0 = *(const s8v*)wb;
        s8v w1 = *(const s8v*)(wb + 512);
        #pragma unroll
        for (int u = 0; u < 2; ++u) {
          f4v acc = {bkf[t], bkf[t], bkf[t], bkf[t]};
          acc = MFMA(xA[u][0], w0, acc);
          acc = MFMA(xA[u][1], w1, acc);
          const float qv = bf2f((unsigned short)qbuf[(pp+u)*HSTRIDE + 16*t + c]);
          #pragma unroll
          for (int r = 0; r < 4; ++r) hC[u][t][r] = qv - acc[r] + pe[u][t][r];
        }
      }
      #pragma unroll
      for (int u = 0; u < 2; ++u)
        #pragma unroll
        for (int r = 0; r < 4; ++r) {
          u2v pv = { pk2(hC[u][0][r], hC[u][1][r]), pk2(hC[u][2][r], hC[u][3][r]) };
          *(u2v*)&HB[u][(4*lq + r)*HSTRIDE + 4*c] = pv;
        }
      #pragma unroll
      for (int u = 0; u < 2; ++u) {
        hA[u][0] = *(const s8v*)&HB[u][c*HSTRIDE + 8*lq];
        hA[u][1] = *(const s8v*)&HB[u][c*HSTRIDE + 32 + 8*lq];
      }
    }

    // a1 = relu(h @ Wa1^T + ba1)  (mat2) ; RT
    s8v aA[2][2];
    {
      f4v a1[2][4];
      #pragma unroll
      for (int t = 0; t < 4; ++t) {
        const short* wb = &wlds[(2*512 + 2*t*64 + lane) * 8];
        s8v w0 = *(const s8v*)wb;
        s8v w1 = *(const s8v*)(wb + 512);
        #pragma unroll
        for (int u = 0; u < 2; ++u) {
          f4v acc = {ba1f[t], ba1f[t], ba1f[t], ba1f[t]};
          acc = MFMA(hA[u][0], w0, acc);
          acc = MFMA(hA[u][1], w1, acc);
          #pragma unroll
          for (int r = 0; r < 4; ++r) acc[r] = fmaxf(acc[r], 0.0f);
          a1[u][t] = acc;
        }
      }
      #pragma unroll
      for (int u = 0; u < 2; ++u)
        #pragma unroll
        for (int r = 0; r < 4; ++r) {
          u2v pv = { pk2(a1[u][0][r], a1[u][1][r]), pk2(a1[u][2][r], a1[u][3][r]) };
          *(u2v*)&HB[u][(4*lq + r)*HSTRIDE + 4*c] = pv;
        }
      #pragma unroll
      for (int u = 0; u < 2; ++u) {
        aA[u][0] = *(const s8v*)&HB[u][c*HSTRIDE + 8*lq];
        aA[u][1] = *(const s8v*)&HB[u][c*HSTRIDE + 32 + 8*lq];
      }
    }

    // logits (mat3) + softmax + v matmul (register frags) + reduce
    f4v lg[2][4];
    #pragma unroll
    for (int t = 0; t < 4; ++t) {
      const short* wb = &wlds[(3*512 + 2*t*64 + lane) * 8];
      s8v w0 = *(const s8v*)wb;
      s8v w1 = *(const s8v*)(wb + 512);
      #pragma unroll
      for (int u = 0; u < 2; ++u) {
        f4v acc = {ba2f[t], ba2f[t], ba2f[t], ba2f[t]};
        acc = MFMA(aA[u][0], w0, acc);
        acc = MFMA(aA[u][1], w1, acc);
        lg[u][t] = acc;
      }
    }

    #pragma unroll
    for (int u = 0; u < 2; ++u) {
      f4v at[4];
      #pragma unroll
      for (int t = 0; t < 4; ++t) {
        f4v l = lg[u][t];
        float mx = fmaxf(fmaxf(l[0], l[1]), fmaxf(l[2], l[3]));
        mx = fmaxf(mx, __shfl_xor(mx, 16));
        mx = fmaxf(mx, __shfl_xor(mx, 32));
        f4v e;
        #pragma unroll
        for (int r = 0; r < 4; ++r) e[r] = exp2f((l[r] - mx) * 0.18033688011112043f);
        float s = e[0] + e[1] + e[2] + e[3];
        s += __shfl_xor(s, 16);
        s += __shfl_xor(s, 32);
        const float ri = 1.0f / s;
        #pragma unroll
        for (int r = 0; r < 4; ++r) at[t][r] = e[r] * ri;
      }
      #pragma unroll
      for (int t = 0; t < 4; ++t) {
        f4v acc = {bvf[t], bvf[t], bvf[t], bvf[t]};
        acc = MFMA(xA[u][0], wvf[2*t+0], acc);
        acc = MFMA(xA[u][1], wvf[2*t+1], acc);
        float pr = 0.0f;
        #pragma unroll
        for (int r = 0; r < 4; ++r) pr += at[t][r] * (acc[r] + pe[u][t][r]);
        pr += __shfl_xor(pr, 16);
        pr += __shfl_xor(pr, 32);
        if (lq == 0) qbuf[(pp+u)*HSTRIDE + 16*t + c] = f2bf(pr);
      }
    }
  }

  // ---- group final: out = res @ W2^T + b2 + raw_feature ----
  {
    s8v resA0 = *(const s8v*)&qbuf[c*HSTRIDE + 8*lq];
    s8v resA1 = *(const s8v*)&qbuf[c*HSTRIDE + 32 + 8*lq];
    #pragma unroll
    for (int t = 0; t < 4; ++t) {
      const float* wr = W2 + (16*t + c)*64 + 8*lq;
      s8v w0 = pack8(*(const f4v*)wr,      *(const f4v*)(wr+4));
      s8v w1 = pack8(*(const f4v*)(wr+32), *(const f4v*)(wr+36));
      f4v acc = {b2f[t], b2f[t], b2f[t], b2f[t]};
      acc = MFMA(resA0, w0, acc);
      acc = MFMA(resA1, w1, acc);
      #pragma unroll
      for (int r = 0; r < 4; ++r) {
        const long pr2 = ptbase + 4*lq + r;
        out[pr2*NC + 16*t + c] = acc[r] + x[pr2*(long)(NK*NC) + 16*t + c];
      }
    }
  }
}

extern "C" void kernel_launch(void* const* d_in, const int* in_sizes, int n_in,
                              void* d_out, int out_size, void* d_ws, size_t ws_size,
                              hipStream_t stream) {
  (void)in_sizes; (void)n_in; (void)out_size; (void)d_ws; (void)ws_size;
  const float* x   = (const float*)d_in[0];
  const float* xyz = (const float*)d_in[1];
  const float* Wq  = (const float*)d_in[2];
  const float* bq  = (const float*)d_in[3];
  const float* Wk  = (const float*)d_in[4];
  const float* bk  = (const float*)d_in[5];
  const float* Wv  = (const float*)d_in[6];
  const float* bv  = (const float*)d_in[7];
  const float* Wp1 = (const float*)d_in[8];
  const float* bp1 = (const float*)d_in[9];
  const float* Wp2 = (const float*)d_in[10];
  const float* bp2 = (const float*)d_in[11];
  const float* Wa1 = (const float*)d_in[12];
  const float* ba1 = (const float*)d_in[13];
  const float* Wa2 = (const float*)d_in[14];
  const float* ba2 = (const float*)d_in[15];
  const float* W2  = (const float*)d_in[16];
  const float* b2  = (const float*)d_in[17];
  float* out = (float*)d_out;

  lattn_kernel<<<dim3(512), dim3(256), 0, stream>>>(
      x, xyz, Wq, bq, Wk, bk, Wv, bv, Wp1, bp1, Wp2, bp2,
      Wa1, ba1, Wa2, ba2, W2, b2, out);
}